// Round 4
// baseline (387.664 us; speedup 1.0000x reference)
//
#include <hip/hip_runtime.h>

#define NN 50000
#define MPAD 50048   // 782 * 64, padded row count for 64-row GEMM tiles

typedef unsigned short u16;
typedef unsigned int u32;
typedef short s16x8 __attribute__((ext_vector_type(8)));   // 8 bf16 (4 VGPRs)
typedef float f32x4 __attribute__((ext_vector_type(4)));

__device__ inline u16 f2bf(float f) {
    u32 u = __float_as_uint(f);
    u32 r = (u + 0x7FFF + ((u >> 16) & 1)) >> 16;   // RNE
    return (u16)r;
}
__device__ inline float bf2f(u16 s) { return __uint_as_float(((u32)s) << 16); }

template <typename T>
__device__ inline const __attribute__((address_space(1))) T* as_g(const T* p) {
    return (const __attribute__((address_space(1))) T*)p;
}
template <typename T>
__device__ inline __attribute__((address_space(3))) T* as_l(T* p) {
    return (__attribute__((address_space(3))) T*)p;
}

// ---------------- CSR build ----------------
__global__ void k_count(const int* __restrict__ dst, int E, int* __restrict__ deg) {
    int i = blockIdx.x * blockDim.x + threadIdx.x;
    if (i < E) atomicAdd(&deg[dst[i]], 1);
}

__global__ void k_scan1(const int* __restrict__ deg, int n,
                        int* __restrict__ out, int* __restrict__ bsum) {
    __shared__ int s[256];
    int t = threadIdx.x;
    int base = blockIdx.x * 1024;
    int v[4]; int sum = 0;
#pragma unroll
    for (int r = 0; r < 4; r++) {
        int idx = base + t * 4 + r;
        v[r] = (idx < n) ? deg[idx] : 0;
        sum += v[r];
    }
    s[t] = sum; __syncthreads();
    for (int off = 1; off < 256; off <<= 1) {
        int x = (t >= off) ? s[t - off] : 0;
        __syncthreads();
        s[t] += x;
        __syncthreads();
    }
    int excl = s[t] - sum;
    if (t == 255) bsum[blockIdx.x] = s[255];
    int run = excl;
#pragma unroll
    for (int r = 0; r < 4; r++) {
        int idx = base + t * 4 + r;
        if (idx < n) out[idx] = run;
        run += v[r];
    }
}

__global__ void k_scan2(int* __restrict__ bsum, int nb) {
    __shared__ int s[64];
    int t = threadIdx.x;
    int orig = (t < nb) ? bsum[t] : 0;
    s[t] = orig; __syncthreads();
    for (int off = 1; off < 64; off <<= 1) {
        int x = (t >= off) ? s[t - off] : 0;
        __syncthreads();
        s[t] += x;
        __syncthreads();
    }
    if (t < nb) bsum[t] = s[t] - orig;
}

__global__ void k_scan3(int* __restrict__ rowptr, const int* __restrict__ bsum,
                        int n, int E) {
    int i = blockIdx.x * blockDim.x + threadIdx.x;
    if (i < n) rowptr[i] += bsum[i >> 10];
    if (i == 0) rowptr[n] = E;
}

__global__ void k_fill(const int* __restrict__ dst, const int* __restrict__ src, int E,
                       const int* __restrict__ rowptr, int* __restrict__ fpos,
                       int* __restrict__ col) {
    int e = blockIdx.x * blockDim.x + threadIdx.x;
    if (e < E) {
        int d = dst[e];
        int p = atomicAdd(&fpos[d], 1);
        col[rowptr[d] + p] = src[e];
    }
}

// ---------------- casts ----------------
__global__ void k_castx(const float* __restrict__ x, u16* __restrict__ xb) {
    int i = blockIdx.x * 256 + threadIdx.x;
    int idx = i * 4;
    u32 lo = 0, hi = 0;
    if (idx < NN * 128) {
        float4 v = *reinterpret_cast<const float4*>(x + idx);
        lo = (u32)f2bf(v.x) | ((u32)f2bf(v.y) << 16);
        hi = (u32)f2bf(v.z) | ((u32)f2bf(v.w) << 16);
    }
    uint2 o; o.x = lo; o.y = hi;
    *reinterpret_cast<uint2*>(xb + idx) = o;
}

__global__ void k_wcat(const float* __restrict__ Wl, const float* __restrict__ Wr,
                       int K, u16* __restrict__ Wt) {
    int idx = blockIdx.x * 256 + threadIdx.x;
    int KC = 2 * K;
    if (idx >= 256 * KC) return;
    int n = idx / KC;
    int k = idx - n * KC;
    float v = (k < K) ? Wl[(size_t)k * 256 + n] : Wr[(size_t)(k - K) * 256 + n];
    Wt[idx] = f2bf(v);
}

// ---------------- aggregation (segment mean, bf16 in/out) ----------------
// one wave per node; lane covers D/64 features. Neighbor loop unrolled x8
// (8 independent row-gathers in flight per wave for latency hiding).
template <int D>
__global__ __launch_bounds__(256) void k_aggb(
    const u16* __restrict__ H, const int* __restrict__ rowptr,
    const int* __restrict__ col, u16* __restrict__ out) {
    constexpr int PER = D / 64;    // 2 or 4
    int wv = threadIdx.x >> 6, l = threadIdx.x & 63;
    int node = blockIdx.x * 4 + wv;
    if (node >= MPAD) return;
    size_t obase = (size_t)node * D + l * PER;
    if (node >= NN) {
        if (PER == 2) *reinterpret_cast<u32*>(out + obase) = 0;
        else { uint2 z; z.x = 0; z.y = 0; *reinterpret_cast<uint2*>(out + obase) = z; }
        return;
    }
    int beg = rowptr[node], end = rowptr[node + 1];
    float acc[PER];
#pragma unroll
    for (int j = 0; j < PER; j++) acc[j] = 0.f;

    int c = beg;
    if (PER == 2) {
        const int fo = l * 2;
        for (; c + 8 <= end; c += 8) {
            u32 v[8];
#pragma unroll
            for (int u = 0; u < 8; ++u)
                v[u] = *reinterpret_cast<const u32*>(H + (size_t)col[c + u] * D + fo);
#pragma unroll
            for (int u = 0; u < 8; ++u) {
                acc[0] += bf2f((u16)(v[u] & 0xFFFF));
                acc[1] += bf2f((u16)(v[u] >> 16));
            }
        }
        for (; c < end; ++c) {
            u32 v = *reinterpret_cast<const u32*>(H + (size_t)col[c] * D + fo);
            acc[0] += bf2f((u16)(v & 0xFFFF));
            acc[1] += bf2f((u16)(v >> 16));
        }
    } else {
        const int fo = l * 4;
        for (; c + 8 <= end; c += 8) {
            uint2 v[8];
#pragma unroll
            for (int u = 0; u < 8; ++u)
                v[u] = *reinterpret_cast<const uint2*>(H + (size_t)col[c + u] * D + fo);
#pragma unroll
            for (int u = 0; u < 8; ++u) {
                acc[0] += bf2f((u16)(v[u].x & 0xFFFF));
                acc[1] += bf2f((u16)(v[u].x >> 16));
                acc[2] += bf2f((u16)(v[u].y & 0xFFFF));
                acc[3] += bf2f((u16)(v[u].y >> 16));
            }
        }
        for (; c < end; ++c) {
            uint2 v = *reinterpret_cast<const uint2*>(H + (size_t)col[c] * D + fo);
            acc[0] += bf2f((u16)(v.x & 0xFFFF));
            acc[1] += bf2f((u16)(v.x >> 16));
            acc[2] += bf2f((u16)(v.y & 0xFFFF));
            acc[3] += bf2f((u16)(v.y >> 16));
        }
    }
    float inv = 1.f / fmaxf((float)(end - beg), 1.f);
    if (PER == 2) {
        u32 o = (u32)f2bf(acc[0] * inv) | ((u32)f2bf(acc[1] * inv) << 16);
        *reinterpret_cast<u32*>(out + obase) = o;
    } else {
        uint2 o;
        o.x = (u32)f2bf(acc[0] * inv) | ((u32)f2bf(acc[1] * inv) << 16);
        o.y = (u32)f2bf(acc[2] * inv) | ((u32)f2bf(acc[3] * inv) << 16);
        *reinterpret_cast<uint2*>(out + obase) = o;
    }
}

// ---------------- MFMA GEMM: out = epi([agg,h] @ Wt^T + b) ----------------
// BM=64, BN=256, BK=64. 4 waves; wave w owns cols w*64..w*64+63.
// A tile in LDS (8KB, double-buffered, XOR-swizzled, global_load_lds);
// B (weights, L2-resident) loaded per-wave DIRECT TO REGISTERS in MFMA
// fragment layout -> no B through LDS, 5x less staging, tiny barrier drain.
template <int K, int MODE>   // MODE 0: relu -> bf16 store; MODE 1: JK-max -> f32 out
__global__ __launch_bounds__(256) void k_mgemm(
    const u16* __restrict__ Aagg, const u16* __restrict__ Ah,
    const u16* __restrict__ Wt, const float* __restrict__ bias,
    const u16* __restrict__ h1b, const u16* __restrict__ h2b,
    u16* __restrict__ outb, float* __restrict__ outf) {
    constexpr int KC = 2 * K;
    constexpr int NSTEP = KC / 64;
    __shared__ u16 sA[2 * 64 * 64];    // 16KB, double-buffered
    int tid = threadIdx.x;
    int w = tid >> 6, l = tid & 63;
    int row0 = blockIdx.x * 64;
    int lr = l & 15, lk = l >> 4;

    f32x4 acc[4][4];
#pragma unroll
    for (int m = 0; m < 4; m++)
#pragma unroll
        for (int n = 0; n < 4; n++) acc[m][n] = (f32x4){0.f, 0.f, 0.f, 0.f};

    auto stageA = [&](int buf, int st) {
        int kk = st * 64;
        const u16* Ab = (kk < K) ? Aagg : Ah;
        int koff = (kk < K) ? kk : kk - K;
#pragma unroll
        for (int s = 0; s < 2; ++s) {
            int p = s * 256 + tid;
            int r = p >> 3, c = p & 7;
            int g = c ^ (r & 7);
            const u16* ga = Ab + (size_t)(row0 + r) * K + koff + g * 8;
            u16* lb = sA + buf * 4096 + (size_t)(s * 256 + (tid & ~63)) * 8;
            __builtin_amdgcn_global_load_lds(as_g(ga), as_l(lb), 16, 0, 0);
        }
    };

    stageA(0, 0);
    for (int st = 0; st < NSTEP; ++st) {
        __syncthreads();                       // buf[st&1] staged (vmcnt drained)
        if (st + 1 < NSTEP) stageA((st + 1) & 1, st + 1);
        int kk = st * 64;
        const char* sAb = reinterpret_cast<const char*>(sA) + (st & 1) * 8192;
#pragma unroll
        for (int kk2 = 0; kk2 < 2; ++kk2) {
            s16x8 bv[4], av[4];
#pragma unroll
            for (int n = 0; n < 4; ++n) {
                const u16* gb = Wt + (size_t)(w * 64 + n * 16 + lr) * KC +
                                kk + kk2 * 32 + lk * 8;
                bv[n] = *reinterpret_cast<const s16x8*>(gb);
            }
#pragma unroll
            for (int m = 0; m < 4; ++m) {
                int off = (m * 16 + lr) * 128 + (((kk2 * 4 + lk) ^ (lr & 7)) << 4);
                av[m] = *reinterpret_cast<const s16x8*>(sAb + off);
            }
#pragma unroll
            for (int m = 0; m < 4; ++m)
#pragma unroll
                for (int n = 0; n < 4; ++n)
                    acc[m][n] = __builtin_amdgcn_mfma_f32_16x16x32_bf16(
                        av[m], bv[n], acc[m][n], 0, 0, 0);
        }
    }

    float bb[4];
#pragma unroll
    for (int n = 0; n < 4; ++n) bb[n] = bias[w * 64 + n * 16 + lr];
#pragma unroll
    for (int m = 0; m < 4; ++m) {
#pragma unroll
        for (int n = 0; n < 4; ++n) {
            int col = w * 64 + n * 16 + lr;
#pragma unroll
            for (int i = 0; i < 4; ++i) {
                int row = row0 + m * 16 + lk * 4 + i;
                size_t o = (size_t)row * 256 + col;
                float z = acc[m][n][i] + bb[n];
                if (MODE == 0) {
                    z = fmaxf(z, 0.f);
                    outb[o] = f2bf(z);
                } else {
                    if (row < NN) {
                        z = fmaxf(z, fmaxf(bf2f(h1b[o]), bf2f(h2b[o])));
                        outf[o] = z;
                    }
                }
            }
        }
    }
}

extern "C" void kernel_launch(void* const* d_in, const int* in_sizes, int n_in,
                              void* d_out, int out_size, void* d_ws, size_t ws_size,
                              hipStream_t stream) {
    const float* x   = (const float*)d_in[0];
    const int*   ei  = (const int*)d_in[1];
    const float* Wl0 = (const float*)d_in[2];
    const float* bl0 = (const float*)d_in[3];
    const float* Wr0 = (const float*)d_in[4];
    const float* Wl1 = (const float*)d_in[5];
    const float* bl1 = (const float*)d_in[6];
    const float* Wr1 = (const float*)d_in[7];
    const float* Wl2 = (const float*)d_in[8];
    const float* bl2 = (const float*)d_in[9];
    const float* Wr2 = (const float*)d_in[10];
    float* out = (float*)d_out;

    const int N = NN;
    const int E = in_sizes[1] / 2;
    const int* dst = ei;          // edge_index[0]
    const int* src = ei + E;      // edge_index[1]

    char* wsp = (char*)d_ws;
    size_t off = 0;
    auto carve = [&](size_t bytes) {
        char* p = wsp + off;
        off += (bytes + 255) & ~(size_t)255;
        return p;
    };
    int* deg    = (int*)carve((size_t)N * 4);
    int* rowptr = (int*)carve((size_t)(N + 1) * 4);
    int* fpos   = (int*)carve((size_t)N * 4);
    int* bsum   = (int*)carve(64 * 4);
    int* colb   = (int*)carve((size_t)E * 4);
    u16* xb     = (u16*)carve((size_t)MPAD * 128 * 2);
    u16* aggb   = (u16*)carve((size_t)MPAD * 256 * 2);
    u16* h1b    = (u16*)carve((size_t)MPAD * 256 * 2);
    u16* h2b    = (u16*)carve((size_t)MPAD * 256 * 2);
    u16* Wt0    = (u16*)carve((size_t)256 * 256 * 2);
    u16* Wt1    = (u16*)carve((size_t)256 * 512 * 2);
    u16* Wt2    = (u16*)carve((size_t)256 * 512 * 2);
    (void)ws_size; (void)n_in; (void)out_size;

    hipMemsetAsync(deg, 0, (size_t)N * 4, stream);
    hipMemsetAsync(fpos, 0, (size_t)N * 4, stream);

    k_count<<<(E + 255) / 256, 256, 0, stream>>>(dst, E, deg);
    int nb = (N + 1023) / 1024;   // 49
    k_scan1<<<nb, 256, 0, stream>>>(deg, N, rowptr, bsum);
    k_scan2<<<1, 64, 0, stream>>>(bsum, nb);
    k_scan3<<<(N + 255) / 256, 256, 0, stream>>>(rowptr, bsum, N, E);
    k_fill<<<(E + 255) / 256, 256, 0, stream>>>(dst, src, E, rowptr, fpos, colb);

    // casts
    k_castx<<<(MPAD * 128 / 4) / 256, 256, 0, stream>>>(x, xb);
    k_wcat<<<256, 256, 0, stream>>>(Wl0, Wr0, 128, Wt0);
    k_wcat<<<512, 256, 0, stream>>>(Wl1, Wr1, 256, Wt1);
    k_wcat<<<512, 256, 0, stream>>>(Wl2, Wr2, 256, Wt2);

    const int GB = MPAD / 64;   // 782 blocks
    const int GA = MPAD / 4;    // 12512 blocks

    // layer 0: K=128
    k_aggb<128><<<GA, 256, 0, stream>>>(xb, rowptr, colb, aggb);
    k_mgemm<128, 0><<<GB, 256, 0, stream>>>(aggb, xb, Wt0, bl0, nullptr, nullptr,
                                            h1b, nullptr);
    // layer 1: K=256
    k_aggb<256><<<GA, 256, 0, stream>>>(h1b, rowptr, colb, aggb);
    k_mgemm<256, 0><<<GB, 256, 0, stream>>>(aggb, h1b, Wt1, bl1, nullptr, nullptr,
                                            h2b, nullptr);
    // layer 2: K=256, JK-max epilogue
    k_aggb<256><<<GA, 256, 0, stream>>>(h2b, rowptr, colb, aggb);
    k_mgemm<256, 1><<<GB, 256, 0, stream>>>(aggb, h2b, Wt2, bl2, h1b, h2b,
                                            nullptr, out);
}

// Round 5
// 359.249 us; speedup vs baseline: 1.0791x; 1.0791x over previous
//
#include <hip/hip_runtime.h>

#define NN 50000
#define MPAD 50048   // 782 * 64, padded row count for 64-row GEMM tiles

typedef unsigned short u16;
typedef unsigned int u32;
typedef short s16x8 __attribute__((ext_vector_type(8)));   // 8 bf16 (4 VGPRs)
typedef float f32x4 __attribute__((ext_vector_type(4)));

__device__ inline u16 f2bf(float f) {
    u32 u = __float_as_uint(f);
    u32 r = (u + 0x7FFF + ((u >> 16) & 1)) >> 16;   // RNE
    return (u16)r;
}
__device__ inline float bf2f(u16 s) { return __uint_as_float(((u32)s) << 16); }

template <typename T>
__device__ inline const __attribute__((address_space(1))) T* as_g(const T* p) {
    return (const __attribute__((address_space(1))) T*)p;
}
template <typename T>
__device__ inline __attribute__((address_space(3))) T* as_l(T* p) {
    return (__attribute__((address_space(3))) T*)p;
}

// ---------------- CSR build ----------------
__global__ void k_count(const int* __restrict__ dst, int E, int* __restrict__ deg) {
    int i = blockIdx.x * blockDim.x + threadIdx.x;
    if (i < E) atomicAdd(&deg[dst[i]], 1);
}

__global__ void k_scan1(const int* __restrict__ deg, int n,
                        int* __restrict__ out, int* __restrict__ bsum) {
    __shared__ int s[256];
    int t = threadIdx.x;
    int base = blockIdx.x * 1024;
    int v[4]; int sum = 0;
#pragma unroll
    for (int r = 0; r < 4; r++) {
        int idx = base + t * 4 + r;
        v[r] = (idx < n) ? deg[idx] : 0;
        sum += v[r];
    }
    s[t] = sum; __syncthreads();
    for (int off = 1; off < 256; off <<= 1) {
        int x = (t >= off) ? s[t - off] : 0;
        __syncthreads();
        s[t] += x;
        __syncthreads();
    }
    int excl = s[t] - sum;
    if (t == 255) bsum[blockIdx.x] = s[255];
    int run = excl;
#pragma unroll
    for (int r = 0; r < 4; r++) {
        int idx = base + t * 4 + r;
        if (idx < n) out[idx] = run;
        run += v[r];
    }
}

__global__ void k_scan2(int* __restrict__ bsum, int nb) {
    __shared__ int s[64];
    int t = threadIdx.x;
    int orig = (t < nb) ? bsum[t] : 0;
    s[t] = orig; __syncthreads();
    for (int off = 1; off < 64; off <<= 1) {
        int x = (t >= off) ? s[t - off] : 0;
        __syncthreads();
        s[t] += x;
        __syncthreads();
    }
    if (t < nb) bsum[t] = s[t] - orig;
}

__global__ void k_scan3(int* __restrict__ rowptr, const int* __restrict__ bsum,
                        int n, int E) {
    int i = blockIdx.x * blockDim.x + threadIdx.x;
    if (i < n) rowptr[i] += bsum[i >> 10];
    if (i == 0) rowptr[n] = E;
}

__global__ void k_fill(const int* __restrict__ dst, const int* __restrict__ src, int E,
                       const int* __restrict__ rowptr, int* __restrict__ fpos,
                       int* __restrict__ col) {
    int e = blockIdx.x * blockDim.x + threadIdx.x;
    if (e < E) {
        int d = dst[e];
        int p = atomicAdd(&fpos[d], 1);
        col[rowptr[d] + p] = src[e];
    }
}

// ---------------- casts ----------------
__global__ void k_castx(const float* __restrict__ x, u16* __restrict__ xb) {
    int i = blockIdx.x * 256 + threadIdx.x;
    int idx = i * 4;
    u32 lo = 0, hi = 0;
    if (idx < NN * 128) {
        float4 v = *reinterpret_cast<const float4*>(x + idx);
        lo = (u32)f2bf(v.x) | ((u32)f2bf(v.y) << 16);
        hi = (u32)f2bf(v.z) | ((u32)f2bf(v.w) << 16);
    }
    uint2 o; o.x = lo; o.y = hi;
    *reinterpret_cast<uint2*>(xb + idx) = o;
}

// Pack weights into MFMA-fragment-interleaved order:
// Wp[((q*16 + c)*64 + l)*8 + j] = W[k][n]  with n = c*16 + (l&15),
// k = q*32 + (l>>4)*8 + j  (k<K -> Wl, else Wr).  One wave-fragment load
// (64 lanes x 16B) is then 1KB CONTIGUOUS -> single coalesced transaction.
__global__ void k_wpack(const float* __restrict__ Wl, const float* __restrict__ Wr,
                        int K, u16* __restrict__ Wp) {
    int idx = blockIdx.x * 256 + threadIdx.x;
    int KC = 2 * K;
    if (idx >= 256 * KC) return;
    int j = idx & 7;
    int l = (idx >> 3) & 63;
    int c = (idx >> 9) & 15;
    int q = idx >> 13;
    int n = c * 16 + (l & 15);
    int k = q * 32 + (l >> 4) * 8 + j;
    float v = (k < K) ? Wl[(size_t)k * 256 + n] : Wr[(size_t)(k - K) * 256 + n];
    Wp[idx] = f2bf(v);
}

// ---------------- aggregation (segment mean, bf16 in/out) ----------------
// one wave per node; lane covers D/64 features. Neighbor loop unrolled x8
// (8 independent row-gathers in flight per wave for latency hiding).
template <int D>
__global__ __launch_bounds__(256) void k_aggb(
    const u16* __restrict__ H, const int* __restrict__ rowptr,
    const int* __restrict__ col, u16* __restrict__ out) {
    constexpr int PER = D / 64;    // 2 or 4
    int wv = threadIdx.x >> 6, l = threadIdx.x & 63;
    int node = blockIdx.x * 4 + wv;
    if (node >= MPAD) return;
    size_t obase = (size_t)node * D + l * PER;
    if (node >= NN) {
        if (PER == 2) *reinterpret_cast<u32*>(out + obase) = 0;
        else { uint2 z; z.x = 0; z.y = 0; *reinterpret_cast<uint2*>(out + obase) = z; }
        return;
    }
    int beg = rowptr[node], end = rowptr[node + 1];
    float acc[PER];
#pragma unroll
    for (int j = 0; j < PER; j++) acc[j] = 0.f;

    int c = beg;
    if (PER == 2) {
        const int fo = l * 2;
        for (; c + 8 <= end; c += 8) {
            u32 v[8];
#pragma unroll
            for (int u = 0; u < 8; ++u)
                v[u] = *reinterpret_cast<const u32*>(H + (size_t)col[c + u] * D + fo);
#pragma unroll
            for (int u = 0; u < 8; ++u) {
                acc[0] += bf2f((u16)(v[u] & 0xFFFF));
                acc[1] += bf2f((u16)(v[u] >> 16));
            }
        }
        for (; c < end; ++c) {
            u32 v = *reinterpret_cast<const u32*>(H + (size_t)col[c] * D + fo);
            acc[0] += bf2f((u16)(v & 0xFFFF));
            acc[1] += bf2f((u16)(v >> 16));
        }
    } else {
        const int fo = l * 4;
        for (; c + 8 <= end; c += 8) {
            uint2 v[8];
#pragma unroll
            for (int u = 0; u < 8; ++u)
                v[u] = *reinterpret_cast<const uint2*>(H + (size_t)col[c + u] * D + fo);
#pragma unroll
            for (int u = 0; u < 8; ++u) {
                acc[0] += bf2f((u16)(v[u].x & 0xFFFF));
                acc[1] += bf2f((u16)(v[u].x >> 16));
                acc[2] += bf2f((u16)(v[u].y & 0xFFFF));
                acc[3] += bf2f((u16)(v[u].y >> 16));
            }
        }
        for (; c < end; ++c) {
            uint2 v = *reinterpret_cast<const uint2*>(H + (size_t)col[c] * D + fo);
            acc[0] += bf2f((u16)(v.x & 0xFFFF));
            acc[1] += bf2f((u16)(v.x >> 16));
            acc[2] += bf2f((u16)(v.y & 0xFFFF));
            acc[3] += bf2f((u16)(v.y >> 16));
        }
    }
    float inv = 1.f / fmaxf((float)(end - beg), 1.f);
    if (PER == 2) {
        u32 o = (u32)f2bf(acc[0] * inv) | ((u32)f2bf(acc[1] * inv) << 16);
        *reinterpret_cast<u32*>(out + obase) = o;
    } else {
        uint2 o;
        o.x = (u32)f2bf(acc[0] * inv) | ((u32)f2bf(acc[1] * inv) << 16);
        o.y = (u32)f2bf(acc[2] * inv) | ((u32)f2bf(acc[3] * inv) << 16);
        *reinterpret_cast<uint2*>(out + obase) = o;
    }
}

// ---------------- MFMA GEMM: out = epi([agg,h] @ W + b) ----------------
// BM=64, BN=256, BK=64. 4 waves; wave w owns cols w*64..w*64+63.
// A tile in LDS (8KB x2, double-buffered, XOR-swizzled, global_load_lds).
// B from packed Wp DIRECT TO REGISTERS: each fragment load is one coalesced
// 1KB wave transaction (L2-resident). Load order per step: bv FIRST, then
// next A-stage DMA -> compiler can wait bv with vmcnt(2), A stays in flight.
template <int K, int MODE>   // MODE 0: relu -> bf16 store; MODE 1: JK-max -> f32 out
__global__ __launch_bounds__(256) void k_mgemm(
    const u16* __restrict__ Aagg, const u16* __restrict__ Ah,
    const u16* __restrict__ Wp, const float* __restrict__ bias,
    const u16* __restrict__ h1b, const u16* __restrict__ h2b,
    u16* __restrict__ outb, float* __restrict__ outf) {
    constexpr int KC = 2 * K;
    constexpr int NSTEP = KC / 64;
    __shared__ u16 sA[2 * 64 * 64];    // 16KB, double-buffered
    int tid = threadIdx.x;
    int w = tid >> 6, l = tid & 63;
    int row0 = blockIdx.x * 64;
    int lr = l & 15, lk = l >> 4;

    f32x4 acc[4][4];
#pragma unroll
    for (int m = 0; m < 4; m++)
#pragma unroll
        for (int n = 0; n < 4; n++) acc[m][n] = (f32x4){0.f, 0.f, 0.f, 0.f};

    auto stageA = [&](int buf, int st) {
        int kk = st * 64;
        const u16* Ab = (kk < K) ? Aagg : Ah;
        int koff = (kk < K) ? kk : kk - K;
#pragma unroll
        for (int s = 0; s < 2; ++s) {
            int p = s * 256 + tid;
            int r = p >> 3, c = p & 7;
            int g = c ^ (r & 7);
            const u16* ga = Ab + (size_t)(row0 + r) * K + koff + g * 8;
            u16* lb = sA + buf * 4096 + (size_t)(s * 256 + (tid & ~63)) * 8;
            __builtin_amdgcn_global_load_lds(as_g(ga), as_l(lb), 16, 0, 0);
        }
    };

    stageA(0, 0);
    for (int st = 0; st < NSTEP; ++st) {
        __syncthreads();                       // buf[st&1] staged (vmcnt drained)
        // B fragments for this step: 8 coalesced 16B/lane loads, issued FIRST
        s16x8 bv[2][4];
#pragma unroll
        for (int kk2 = 0; kk2 < 2; ++kk2) {
            int q = st * 2 + kk2;
#pragma unroll
            for (int n = 0; n < 4; ++n) {
                const u16* gb = Wp + ((size_t)(q * 16 + w * 4 + n) * 64 + l) * 8;
                bv[kk2][n] = *reinterpret_cast<const s16x8*>(gb);
            }
        }
        if (st + 1 < NSTEP) stageA((st + 1) & 1, st + 1);
        const char* sAb = reinterpret_cast<const char*>(sA) + (st & 1) * 8192;
#pragma unroll
        for (int kk2 = 0; kk2 < 2; ++kk2) {
            s16x8 av[4];
#pragma unroll
            for (int m = 0; m < 4; ++m) {
                int off = (m * 16 + lr) * 128 + (((kk2 * 4 + lk) ^ (lr & 7)) << 4);
                av[m] = *reinterpret_cast<const s16x8*>(sAb + off);
            }
#pragma unroll
            for (int m = 0; m < 4; ++m)
#pragma unroll
                for (int n = 0; n < 4; ++n)
                    acc[m][n] = __builtin_amdgcn_mfma_f32_16x16x32_bf16(
                        av[m], bv[kk2][n], acc[m][n], 0, 0, 0);
        }
    }

    float bb[4];
#pragma unroll
    for (int n = 0; n < 4; ++n) bb[n] = bias[w * 64 + n * 16 + lr];
#pragma unroll
    for (int m = 0; m < 4; ++m) {
#pragma unroll
        for (int n = 0; n < 4; ++n) {
            int col = w * 64 + n * 16 + lr;
#pragma unroll
            for (int i = 0; i < 4; ++i) {
                int row = row0 + m * 16 + lk * 4 + i;
                size_t o = (size_t)row * 256 + col;
                float z = acc[m][n][i] + bb[n];
                if (MODE == 0) {
                    z = fmaxf(z, 0.f);
                    outb[o] = f2bf(z);
                } else {
                    if (row < NN) {
                        z = fmaxf(z, fmaxf(bf2f(h1b[o]), bf2f(h2b[o])));
                        outf[o] = z;
                    }
                }
            }
        }
    }
}

extern "C" void kernel_launch(void* const* d_in, const int* in_sizes, int n_in,
                              void* d_out, int out_size, void* d_ws, size_t ws_size,
                              hipStream_t stream) {
    const float* x   = (const float*)d_in[0];
    const int*   ei  = (const int*)d_in[1];
    const float* Wl0 = (const float*)d_in[2];
    const float* bl0 = (const float*)d_in[3];
    const float* Wr0 = (const float*)d_in[4];
    const float* Wl1 = (const float*)d_in[5];
    const float* bl1 = (const float*)d_in[6];
    const float* Wr1 = (const float*)d_in[7];
    const float* Wl2 = (const float*)d_in[8];
    const float* bl2 = (const float*)d_in[9];
    const float* Wr2 = (const float*)d_in[10];
    float* out = (float*)d_out;

    const int N = NN;
    const int E = in_sizes[1] / 2;
    const int* dst = ei;          // edge_index[0]
    const int* src = ei + E;      // edge_index[1]

    char* wsp = (char*)d_ws;
    size_t off = 0;
    auto carve = [&](size_t bytes) {
        char* p = wsp + off;
        off += (bytes + 255) & ~(size_t)255;
        return p;
    };
    int* deg    = (int*)carve((size_t)N * 4);
    int* rowptr = (int*)carve((size_t)(N + 1) * 4);
    int* fpos   = (int*)carve((size_t)N * 4);
    int* bsum   = (int*)carve(64 * 4);
    int* colb   = (int*)carve((size_t)E * 4);
    u16* xb     = (u16*)carve((size_t)MPAD * 128 * 2);
    u16* aggb   = (u16*)carve((size_t)MPAD * 256 * 2);
    u16* h1b    = (u16*)carve((size_t)MPAD * 256 * 2);
    u16* h2b    = (u16*)carve((size_t)MPAD * 256 * 2);
    u16* Wp0    = (u16*)carve((size_t)256 * 256 * 2);
    u16* Wp1    = (u16*)carve((size_t)256 * 512 * 2);
    u16* Wp2    = (u16*)carve((size_t)256 * 512 * 2);
    (void)ws_size; (void)n_in; (void)out_size;

    hipMemsetAsync(deg, 0, (size_t)N * 4, stream);
    hipMemsetAsync(fpos, 0, (size_t)N * 4, stream);

    k_count<<<(E + 255) / 256, 256, 0, stream>>>(dst, E, deg);
    int nb = (N + 1023) / 1024;   // 49
    k_scan1<<<nb, 256, 0, stream>>>(deg, N, rowptr, bsum);
    k_scan2<<<1, 64, 0, stream>>>(bsum, nb);
    k_scan3<<<(N + 255) / 256, 256, 0, stream>>>(rowptr, bsum, N, E);
    k_fill<<<(E + 255) / 256, 256, 0, stream>>>(dst, src, E, rowptr, fpos, colb);

    // casts / weight packing
    k_castx<<<(MPAD * 128 / 4) / 256, 256, 0, stream>>>(x, xb);
    k_wpack<<<256, 256, 0, stream>>>(Wl0, Wr0, 128, Wp0);
    k_wpack<<<512, 256, 0, stream>>>(Wl1, Wr1, 256, Wp1);
    k_wpack<<<512, 256, 0, stream>>>(Wl2, Wr2, 256, Wp2);

    const int GB = MPAD / 64;   // 782 blocks
    const int GA = MPAD / 4;    // 12512 blocks

    // layer 0: K=128
    k_aggb<128><<<GA, 256, 0, stream>>>(xb, rowptr, colb, aggb);
    k_mgemm<128, 0><<<GB, 256, 0, stream>>>(aggb, xb, Wp0, bl0, nullptr, nullptr,
                                            h1b, nullptr);
    // layer 1: K=256
    k_aggb<256><<<GA, 256, 0, stream>>>(h1b, rowptr, colb, aggb);
    k_mgemm<256, 0><<<GB, 256, 0, stream>>>(aggb, h1b, Wp1, bl1, nullptr, nullptr,
                                            h2b, nullptr);
    // layer 2: K=256, JK-max epilogue
    k_aggb<256><<<GA, 256, 0, stream>>>(h2b, rowptr, colb, aggb);
    k_mgemm<256, 1><<<GB, 256, 0, stream>>>(aggb, h2b, Wp2, bl2, h1b, h2b,
                                            nullptr, out);
}